// Round 2
// baseline (485.906 us; speedup 1.0000x reference)
//
#include <hip/hip_runtime.h>

// RGCN pruned to the 2-hop cone of the first 1024 nodes.
// R2: linear1 as bf16 MFMA GEMM; compacted edge lists for scatter;
// Acat memsets fused into gather (zero msg region there).

#define N_NODES 100000
#define N_EDGES 400000
#define IN_DIM  768
#define HID     256
#define OUT_DIM 128
#define NREL    3
#define BATCH   1024
#define KCAT    1024   // HID*(NREL+1)
#define CAP0    32768  // |S0| ~22K
#define CAP1    8192   // |S1| ~5K
#define ECAP1   32768  // edges into S1 ~20K
#define ECAP2   8192   // edges into S2 ~4.1K

typedef __attribute__((ext_vector_type(8))) short bf16x8;
typedef __attribute__((ext_vector_type(4))) float f32x4;

static __device__ __forceinline__ int imin(int a, int b) { return a < b ? a : b; }

static __device__ __forceinline__ unsigned short f2bf(float f) {
    union { float f; unsigned int u; } v; v.f = f;
    unsigned int r = v.u + 0x7FFFu + ((v.u >> 16) & 1u);   // RNE
    return (unsigned short)(r >> 16);
}

// ---------------- set construction ----------------

__global__ void init_need1(int* need1) {
    int i = blockIdx.x * blockDim.x + threadIdx.x;
    if (i < N_NODES) need1[i] = (i < BATCH) ? 1 : 0;
}

// mark sources of edges into S2, and push those edges to elist2
__global__ void mark1c(const int* __restrict__ ei, int* __restrict__ need1,
                       int* __restrict__ elist2, int* __restrict__ ectr2) {
    int e = blockIdx.x * blockDim.x + threadIdx.x;
    if (e >= N_EDGES) return;
    if (ei[N_EDGES + e] < BATCH) {
        need1[ei[e]] = 1;   // benign same-value race
        int p = atomicAdd(ectr2, 1);
        if (p < ECAP2) elist2[p] = e;
    }
}

__global__ void init_need0(const int* __restrict__ map1, int* __restrict__ need0) {
    int i = blockIdx.x * blockDim.x + threadIdx.x;
    if (i < N_NODES) need0[i] = (map1[i] >= 0) ? 1 : 0;
}

// mark sources of edges into S1, and push those edges to elist1
__global__ void mark0c(const int* __restrict__ ei, const int* __restrict__ map1,
                       int* __restrict__ need0,
                       int* __restrict__ elist1, int* __restrict__ ectr1) {
    int e = blockIdx.x * blockDim.x + threadIdx.x;
    if (e >= N_EDGES) return;
    if (map1[ei[N_EDGES + e]] >= 0) {
        need0[ei[e]] = 1;
        int p = atomicAdd(ectr1, 1);
        if (p < ECAP1) elist1[p] = e;
    }
}

__global__ void compact(const int* __restrict__ flag, int* __restrict__ idx,
                        int* __restrict__ map, int* __restrict__ ctr, int cap) {
    int i = blockIdx.x * blockDim.x + threadIdx.x;
    if (i >= N_NODES) return;
    if (flag[i]) {
        int p = atomicAdd(ctr, 1);
        if (p < cap) { idx[p] = i; map[i] = p; }
        else map[i] = -1;
    } else {
        map[i] = -1;
    }
}

// ---------------- gathers (also zero the message region) ----------------

__global__ void gather_rows(const float* __restrict__ hsrc,
                            const int* __restrict__ idx, const int* __restrict__ mapSrc,
                            float* __restrict__ Acat,
                            const int* __restrict__ nptr, int cap) {
    int j = blockIdx.x, c = threadIdx.x;
    int n = imin(*nptr, cap);
    if (j >= n) return;
    int srow = mapSrc[idx[j]];
    float* dp = Acat + (size_t)j * KCAT;
    dp[c]       = (srow >= 0) ? hsrc[(size_t)srow * HID + c] : 0.0f;
    dp[c + 256] = 0.0f;
    dp[c + 512] = 0.0f;
    dp[c + 768] = 0.0f;
}

__global__ void gather_rows_s2(const float* __restrict__ h1c, const int* __restrict__ map1,
                               float* __restrict__ Acat2) {
    int i = blockIdx.x, c = threadIdx.x;
    int srow = map1[i];
    float* dp = Acat2 + (size_t)i * KCAT;
    dp[c]       = (srow >= 0) ? h1c[(size_t)srow * HID + c] : 0.0f;
    dp[c + 256] = 0.0f;
    dp[c + 512] = 0.0f;
    dp[c + 768] = 0.0f;
}

// ---------------- scatter over compacted edge list ----------------
// 64 lanes per edge; lane handles 4 contiguous floats (float4 load + 4 atomics).
__global__ void scatter_c(const int* __restrict__ ei, const int* __restrict__ et,
                          const int* __restrict__ elist, const int* __restrict__ ectr, int ecap,
                          const int* __restrict__ mapSrc, const int* __restrict__ mapDst,
                          const float* __restrict__ hsrc,
                          float* __restrict__ Acat, float* __restrict__ cnt,
                          int cntStride, int dstDirect) {
    int g = blockIdx.x * blockDim.x + threadIdx.x;
    int ii = g >> 6, lane = g & 63;
    int n = imin(*ectr, ecap);
    if (ii >= n) return;
    int e = elist[ii];
    int d = ei[N_EDGES + e];
    int row = dstDirect ? d : mapDst[d];
    if (row < 0) return;
    int s = mapSrc[ei[e]];
    if (s < 0) return;
    int r = et[e];
    float4 v = *(const float4*)(hsrc + (size_t)s * HID + lane * 4);
    float* dp = Acat + (size_t)row * KCAT + HID + (size_t)r * HID + lane * 4;
    atomicAdd(dp + 0, v.x);
    atomicAdd(dp + 1, v.y);
    atomicAdd(dp + 2, v.z);
    atomicAdd(dp + 3, v.w);
    if (lane == 0) atomicAdd(cnt + (size_t)r * cntStride + row, 1.0f);
}

__global__ void normalize_msgs(float* __restrict__ Acat, const float* __restrict__ cnt,
                               int cntStride, const int* __restrict__ nptr, int cap) {
    int j = blockIdx.x, c = threadIdx.x;
    int n = nptr ? imin(*nptr, cap) : cap;
    if (j >= n) return;
    #pragma unroll
    for (int r = 0; r < NREL; r++) {
        float f = cnt[(size_t)r * cntStride + j];
        float s = 1.0f / fmaxf(f, 1.0f);
        Acat[(size_t)j * KCAT + HID + (size_t)r * HID + c] *= s;
    }
}

// ---------------- W1 prep: bf16, transposed, pre-tiled for LDS staging ----------------
// w1s[s][c][j] = bf16(W1[s*32 + j][c]), s<24 (k-step), c<256 (out col), j<32 (k in step)
__global__ void prep_w1(const float* __restrict__ W1, unsigned short* __restrict__ w1s) {
    int t = blockIdx.x * blockDim.x + threadIdx.x;  // < 24*256*32
    int j = t & 31, c = (t >> 5) & 255, s = t >> 13;
    w1s[t] = f2bf(W1[((s * 32 + j) << 8) + c]);
}

// ---------------- linear1: h0c = relu(x[idx0] @ W1 + b1), bf16 MFMA ----------------
// BM=64, BN=256(all), BK=32. 256 threads = 4 waves; wave w owns rows w*16..w*16+15,
// all 256 cols as 16 fragments of 16x16. Frag layouts per guide §3 (m89/m91/m97).
__global__ __launch_bounds__(256) void gemm1_mfma(
    const float* __restrict__ x, const int* __restrict__ idx0,
    const unsigned short* __restrict__ w1s, const float* __restrict__ b1,
    float* __restrict__ h0c, const int* __restrict__ Mptr, int Mcap)
{
    int M = imin(*Mptr, Mcap);
    int bm = blockIdx.x * 64;
    if (bm >= M) return;

    __shared__ unsigned short As[64][40];    // pad 40: 80B row stride, 2-way banks max
    __shared__ unsigned short Bs[256][40];

    int tid = threadIdx.x;
    int w = tid >> 6, lane = tid & 63;
    int l16 = lane & 15, lhi = lane >> 4;    // lhi in 0..3

    // A staging: thread -> (row tid>>2, k-chunk tid&3 of 8 fp32)
    int ar = tid >> 2, ac = tid & 3;
    int gr = idx0[imin(bm + ar, M - 1)];     // clamp; stores are guarded by row<M
    const float* aptr = x + (size_t)gr * IN_DIM + ac * 8;

    f32x4 acc[16];
    #pragma unroll
    for (int i = 0; i < 16; i++) acc[i] = (f32x4)0.0f;

    for (int k0 = 0; k0 < IN_DIM; k0 += 32) {
        // ---- stage A (fp32 -> bf16) ----
        float4 a0 = *(const float4*)(aptr + k0);
        float4 a1 = *(const float4*)(aptr + k0 + 4);
        unsigned int p0 = (unsigned int)f2bf(a0.x) | ((unsigned int)f2bf(a0.y) << 16);
        unsigned int p1 = (unsigned int)f2bf(a0.z) | ((unsigned int)f2bf(a0.w) << 16);
        unsigned int p2 = (unsigned int)f2bf(a1.x) | ((unsigned int)f2bf(a1.y) << 16);
        unsigned int p3 = (unsigned int)f2bf(a1.z) | ((unsigned int)f2bf(a1.w) << 16);
        *(uint4*)&As[ar][ac * 8] = make_uint4(p0, p1, p2, p3);

        // ---- stage B (pre-tiled bf16; coalesced 64B per thread) ----
        const uint4* bsrc = (const uint4*)(w1s + ((size_t)(k0 >> 5) * 256 + tid) * 32);
        int bswz = (tid >> 3) & 3;           // xor-swizzle chunk to kill 8-way write conflict
        uint4 b0 = bsrc[0], b1v = bsrc[1], b2 = bsrc[2], b3 = bsrc[3];
        *(uint4*)&Bs[tid][(0 ^ bswz) * 8] = b0;
        *(uint4*)&Bs[tid][(1 ^ bswz) * 8] = b1v;
        *(uint4*)&Bs[tid][(2 ^ bswz) * 8] = b2;
        *(uint4*)&Bs[tid][(3 ^ bswz) * 8] = b3;
        __syncthreads();

        // ---- MFMA: A frag row = w*16+l16, k = lhi*8..+7 ----
        bf16x8 af = *(bf16x8*)&As[w * 16 + l16][lhi * 8];
        #pragma unroll
        for (int f = 0; f < 16; f++) {
            int col = f * 16 + l16;
            bf16x8 bf = *(bf16x8*)&Bs[col][(lhi ^ ((col >> 3) & 3)) * 8];
            acc[f] = __builtin_amdgcn_mfma_f32_16x16x32_bf16(af, bf, acc[f], 0, 0, 0);
        }
        __syncthreads();
    }

    // epilogue: C/D map col=lane&15, row=(lane>>4)*4+reg (m89/m91)
    #pragma unroll
    for (int f = 0; f < 16; f++) {
        int col = f * 16 + l16;
        float bb = b1[col];
        #pragma unroll
        for (int reg = 0; reg < 4; reg++) {
            int row = bm + w * 16 + lhi * 4 + reg;
            if (row < M) h0c[(size_t)row * HID + col] = fmaxf(acc[f][reg] + bb, 0.0f);
        }
    }
}

// ---------------- fp32 tiled GEMM (conv1/conv2/linear2) ----------------
template<bool RELU>
__global__ __launch_bounds__(256) void gemm_f32(
    const float* __restrict__ A, int lda,
    const float* __restrict__ B, int ldb,
    const float* __restrict__ bias,
    float* __restrict__ C, int ldc,
    const int* __restrict__ Mptr, int Mcap, int K)
{
    constexpr int BM = 64, BN = 64, BK = 16;
    int M = Mptr ? imin(*Mptr, Mcap) : Mcap;
    int bm = blockIdx.x * BM;
    int bn = blockIdx.y * BN;
    if (bm >= M) return;

    __shared__ float As[BK][BM + 4];
    __shared__ float Bs[BK][BN + 4];

    int tid = threadIdx.x;
    int tx = tid & 15, ty = tid >> 4;
    int arow = tid >> 2, akch = tid & 3;
    int brow = tid >> 4, bnch = tid & 15;

    bool rowok = (bm + arow) < M;
    const float* Aptr = A + (size_t)(bm + (rowok ? arow : 0)) * lda + akch * 4;
    const float* Bptr = B + (size_t)brow * ldb + bn + bnch * 4;

    float acc[4][4] = {};

    for (int k0 = 0; k0 < K; k0 += BK) {
        float4 av = rowok ? *(const float4*)(Aptr + k0) : make_float4(0.f, 0.f, 0.f, 0.f);
        float4 bv = *(const float4*)(Bptr + (size_t)k0 * ldb);
        As[akch * 4 + 0][arow] = av.x;
        As[akch * 4 + 1][arow] = av.y;
        As[akch * 4 + 2][arow] = av.z;
        As[akch * 4 + 3][arow] = av.w;
        *(float4*)&Bs[brow][bnch * 4] = bv;
        __syncthreads();
        #pragma unroll
        for (int k = 0; k < BK; k++) {
            float4 a = *(const float4*)&As[k][ty * 4];
            float4 b = *(const float4*)&Bs[k][tx * 4];
            acc[0][0] += a.x * b.x; acc[0][1] += a.x * b.y; acc[0][2] += a.x * b.z; acc[0][3] += a.x * b.w;
            acc[1][0] += a.y * b.x; acc[1][1] += a.y * b.y; acc[1][2] += a.y * b.z; acc[1][3] += a.y * b.w;
            acc[2][0] += a.z * b.x; acc[2][1] += a.z * b.y; acc[2][2] += a.z * b.z; acc[2][3] += a.z * b.w;
            acc[3][0] += a.w * b.x; acc[3][1] += a.w * b.y; acc[3][2] += a.w * b.z; acc[3][3] += a.w * b.w;
        }
        __syncthreads();
    }

    #pragma unroll
    for (int i = 0; i < 4; i++) {
        int row = bm + ty * 4 + i;
        if (row < M) {
            int col = bn + tx * 4;
            float4 o;
            o.x = acc[i][0] + bias[col + 0];
            o.y = acc[i][1] + bias[col + 1];
            o.z = acc[i][2] + bias[col + 2];
            o.w = acc[i][3] + bias[col + 3];
            if (RELU) {
                o.x = fmaxf(o.x, 0.f); o.y = fmaxf(o.y, 0.f);
                o.z = fmaxf(o.z, 0.f); o.w = fmaxf(o.w, 0.f);
            }
            *(float4*)&C[(size_t)row * ldc + col] = o;
        }
    }
}

// ---------------- classifier ----------------
__global__ void classifier_k(const float* __restrict__ h3, const float* __restrict__ Wc,
                             const float* __restrict__ bc, float* __restrict__ out) {
    int row = blockIdx.x;
    int t = threadIdx.x;
    const float* hp = h3 + (size_t)row * OUT_DIM;
    float a = hp[t], b = hp[t + 64];
    float s0 = a * Wc[t * 2 + 0] + b * Wc[(t + 64) * 2 + 0];
    float s1 = a * Wc[t * 2 + 1] + b * Wc[(t + 64) * 2 + 1];
    #pragma unroll
    for (int o = 32; o >= 1; o >>= 1) {
        s0 += __shfl_xor(s0, o);
        s1 += __shfl_xor(s1, o);
    }
    if (t == 0) {
        out[row * 2 + 0] = s0 + bc[0];
        out[row * 2 + 1] = s1 + bc[1];
    }
}

// ---------------- host ----------------

extern "C" void kernel_launch(void* const* d_in, const int* in_sizes, int n_in,
                              void* d_out, int out_size, void* d_ws, size_t ws_size,
                              hipStream_t stream) {
    const float* x      = (const float*)d_in[0];
    const int*   ei     = (const int*)d_in[1];
    const int*   et     = (const int*)d_in[2];
    const float* W1     = (const float*)d_in[4];
    const float* b1     = (const float*)d_in[5];
    const float* c1W    = (const float*)d_in[6];
    const float* c1root = (const float*)d_in[7];
    const float* c1bias = (const float*)d_in[8];
    const float* c2W    = (const float*)d_in[9];
    const float* c2root = (const float*)d_in[10];
    const float* c2bias = (const float*)d_in[11];
    const float* W2     = (const float*)d_in[12];
    const float* b2     = (const float*)d_in[13];
    const float* Wc     = (const float*)d_in[14];
    const float* bc     = (const float*)d_in[15];
    float* out = (float*)d_out;

    char* ws = (char*)d_ws;
    size_t off = 0;
    auto alloc = [&](size_t bytes) -> char* {
        char* p = ws + off;
        off = (off + bytes + 255) & ~(size_t)255;
        return p;
    };

    int* need1 = (int*)alloc(N_NODES * 4);
    int* need0 = (int*)alloc(N_NODES * 4);
    int* map1  = (int*)alloc(N_NODES * 4);
    int* map0  = (int*)alloc(N_NODES * 4);
    int* idx1  = (int*)alloc(CAP1 * 4);
    int* idx0  = (int*)alloc(CAP0 * 4);
    int* elist1 = (int*)alloc(ECAP1 * 4);
    int* elist2 = (int*)alloc(ECAP2 * 4);
    // zero block: 4 counters + relation counts
    size_t zbytes = 4 * 4 + (size_t)NREL * CAP1 * 4 + (size_t)NREL * BATCH * 4;
    char* zblock = alloc(zbytes);
    int*   n1ctr = (int*)zblock;
    int*   n0ctr = n1ctr + 1;
    int*   ectr1 = n1ctr + 2;
    int*   ectr2 = n1ctr + 3;
    float* cnt1  = (float*)(zblock + 16);
    float* cnt2  = cnt1 + (size_t)NREL * CAP1;
    float* h0c   = (float*)alloc((size_t)CAP0 * HID * 4);
    float* Acat1 = (float*)alloc((size_t)CAP1 * KCAT * 4);
    float* h1c   = (float*)alloc((size_t)CAP1 * HID * 4);
    float* Acat2 = (float*)alloc((size_t)BATCH * KCAT * 4);
    float* h2    = (float*)alloc((size_t)BATCH * HID * 4);
    float* h3    = (float*)alloc((size_t)BATCH * OUT_DIM * 4);
    float* Bcat1 = (float*)alloc((size_t)KCAT * HID * 4);
    float* Bcat2 = (float*)alloc((size_t)KCAT * HID * 4);
    unsigned short* w1s = (unsigned short*)alloc((size_t)IN_DIM * HID * 2);
    (void)ws_size; (void)in_sizes; (void)n_in; (void)out_size;

    const int NB = 256;
    dim3 nodeGrid((N_NODES + NB - 1) / NB);
    dim3 edgeGrid((N_EDGES + NB - 1) / NB);

    hipMemsetAsync(zblock, 0, zbytes, stream);
    hipMemcpyAsync(Bcat1, c1root, (size_t)HID * HID * 4, hipMemcpyDeviceToDevice, stream);
    hipMemcpyAsync(Bcat1 + (size_t)HID * HID, c1W, (size_t)NREL * HID * HID * 4, hipMemcpyDeviceToDevice, stream);
    hipMemcpyAsync(Bcat2, c2root, (size_t)HID * HID * 4, hipMemcpyDeviceToDevice, stream);
    hipMemcpyAsync(Bcat2 + (size_t)HID * HID, c2W, (size_t)NREL * HID * HID * 4, hipMemcpyDeviceToDevice, stream);

    prep_w1<<<dim3((IN_DIM * HID) / NB), NB, 0, stream>>>(W1, w1s);

    // dependency cone + compact edge lists
    init_need1<<<nodeGrid, NB, 0, stream>>>(need1);
    mark1c<<<edgeGrid, NB, 0, stream>>>(ei, need1, elist2, ectr2);
    compact<<<nodeGrid, NB, 0, stream>>>(need1, idx1, map1, n1ctr, CAP1);
    init_need0<<<nodeGrid, NB, 0, stream>>>(map1, need0);
    mark0c<<<edgeGrid, NB, 0, stream>>>(ei, map1, need0, elist1, ectr1);
    compact<<<nodeGrid, NB, 0, stream>>>(need0, idx0, map0, n0ctr, CAP0);

    // h0c = relu(x[S0] @ W1 + b1)  — bf16 MFMA
    gemm1_mfma<<<dim3(CAP0 / 64), NB, 0, stream>>>(x, idx0, w1s, b1, h0c, n0ctr, CAP0);

    // conv1
    gather_rows<<<dim3(CAP1), NB, 0, stream>>>(h0c, idx1, map0, Acat1, n1ctr, CAP1);
    scatter_c<<<dim3(ECAP1 * 64 / NB), NB, 0, stream>>>(ei, et, elist1, ectr1, ECAP1,
                                                        map0, map1, h0c, Acat1, cnt1, CAP1, 0);
    normalize_msgs<<<dim3(CAP1), NB, 0, stream>>>(Acat1, cnt1, CAP1, n1ctr, CAP1);
    gemm_f32<false><<<dim3(CAP1 / 64, HID / 64), NB, 0, stream>>>(
        Acat1, KCAT, Bcat1, HID, c1bias, h1c, HID, n1ctr, CAP1, KCAT);

    // conv2 (rows = node ids 0..1023)
    gather_rows_s2<<<dim3(BATCH), NB, 0, stream>>>(h1c, map1, Acat2);
    scatter_c<<<dim3(ECAP2 * 64 / NB), NB, 0, stream>>>(ei, et, elist2, ectr2, ECAP2,
                                                        map1, nullptr, h1c, Acat2, cnt2, BATCH, 1);
    normalize_msgs<<<dim3(BATCH), NB, 0, stream>>>(Acat2, cnt2, BATCH, nullptr, BATCH);
    gemm_f32<false><<<dim3(BATCH / 64, HID / 64), NB, 0, stream>>>(
        Acat2, KCAT, Bcat2, HID, c2bias, h2, HID, nullptr, BATCH, KCAT);

    // linear2 + relu; classifier
    gemm_f32<true><<<dim3(BATCH / 64, OUT_DIM / 64), NB, 0, stream>>>(
        h2, HID, W2, OUT_DIM, b2, h3, OUT_DIM, nullptr, BATCH, HID);
    classifier_k<<<dim3(BATCH), 64, 0, stream>>>(h3, Wc, bc, out);
}

// Round 3
// 411.596 us; speedup vs baseline: 1.1805x; 1.1805x over previous
//
#include <hip/hip_runtime.h>

// RGCN pruned to the 2-hop cone of the first 1024 nodes.
// R3: 11 graph nodes total. All three big GEMMs bf16-MFMA. Gather + normalize
// folded into conv GEMM A-staging. Weight prep (incl. concat-B build) in one
// kernel. lin2+relu+classifier fused.

#define N_NODES 100000
#define N_EDGES 400000
#define IN_DIM  768
#define HID     256
#define OUT_DIM 128
#define NREL    3
#define BATCH   1024
#define KCAT    1024   // HID*(NREL+1)
#define MSGW    768    // NREL*HID
#define CAP0    32768  // |S0| ~23K
#define CAP1    8192   // |S1| ~5K
#define ECAP1   32768  // edges into S1 ~20K
#define ECAP2   8192   // edges into S2 ~4.1K

typedef __attribute__((ext_vector_type(8))) short bf16x8;
typedef __attribute__((ext_vector_type(4))) float f32x4;

static __device__ __forceinline__ int imin(int a, int b) { return a < b ? a : b; }

static __device__ __forceinline__ unsigned short f2bf(float f) {
    union { float f; unsigned int u; } v; v.f = f;
    unsigned int r = v.u + 0x7FFFu + ((v.u >> 16) & 1u);   // RNE
    return (unsigned short)(r >> 16);
}

// ---------------- weight prep: bf16, k-tiled [kstep][col][32] ----------------
__global__ void prep_weights(const float* __restrict__ W1,
                             const float* __restrict__ c1root, const float* __restrict__ c1W,
                             const float* __restrict__ c2root, const float* __restrict__ c2W,
                             unsigned short* __restrict__ w1s,
                             unsigned short* __restrict__ B1s,
                             unsigned short* __restrict__ B2s) {
    int t = blockIdx.x * blockDim.x + threadIdx.x;
    const int S1 = IN_DIM * HID;         // 196608
    const int S2 = KCAT * HID;           // 262144
    if (t < S1) {
        int j = t & 31, c = (t >> 5) & 255, s = t >> 13;
        w1s[t] = f2bf(W1[((s * 32 + j) << 8) + c]);
    } else if (t < S1 + S2) {
        int u = t - S1;
        int j = u & 31, c = (u >> 5) & 255, s = u >> 13;
        int k = s * 32 + j;
        float v = (k < HID) ? c1root[(k << 8) + c] : c1W[((k - HID) << 8) + c];
        B1s[u] = f2bf(v);
    } else if (t < S1 + 2 * S2) {
        int u = t - S1 - S2;
        int j = u & 31, c = (u >> 5) & 255, s = u >> 13;
        int k = s * 32 + j;
        float v = (k < HID) ? c2root[(k << 8) + c] : c2W[((k - HID) << 8) + c];
        B2s[u] = f2bf(v);
    }
}

// ---------------- set construction ----------------

// edges into S2 (dst < BATCH): flag src, append edge
__global__ void mark1c(const int* __restrict__ ei, int* __restrict__ need1,
                       int* __restrict__ elist2, int* __restrict__ ectr2) {
    int e = blockIdx.x * blockDim.x + threadIdx.x;
    if (e >= N_EDGES) return;
    if (ei[N_EDGES + e] < BATCH) {
        need1[ei[e]] = 1;   // benign same-value race
        int p = atomicAdd(ectr2, 1);
        if (p < ECAP2) elist2[p] = e;
    }
}

// edges into S1 (dst < BATCH or flagged): flag src, append edge
__global__ void mark0c(const int* __restrict__ ei, const int* __restrict__ need1,
                       int* __restrict__ need0,
                       int* __restrict__ elist1, int* __restrict__ ectr1) {
    int e = blockIdx.x * blockDim.x + threadIdx.x;
    if (e >= N_EDGES) return;
    int d = ei[N_EDGES + e];
    if (d < BATCH || need1[d]) {
        need0[ei[e]] = 1;
        int p = atomicAdd(ectr1, 1);
        if (p < ECAP1) elist1[p] = e;
    }
}

// both compactions in one node pass (S1 = need1 | i<BATCH; S0 = need0 | S1)
__global__ void compact_both(const int* __restrict__ need1, const int* __restrict__ need0,
                             int* __restrict__ idx1, int* __restrict__ map1, int* __restrict__ n1ctr,
                             int* __restrict__ idx0, int* __restrict__ map0, int* __restrict__ n0ctr) {
    int i = blockIdx.x * blockDim.x + threadIdx.x;
    if (i >= N_NODES) return;
    int f1 = (i < BATCH) | need1[i];
    int f0 = f1 | need0[i];
    if (f1) {
        int p = atomicAdd(n1ctr, 1);
        if (p < CAP1) { idx1[p] = i; map1[i] = p; } else map1[i] = -1;
    } else map1[i] = -1;
    if (f0) {
        int p = atomicAdd(n0ctr, 1);
        if (p < CAP0) { idx0[p] = i; map0[i] = p; } else map0[i] = -1;
    } else map0[i] = -1;
}

// ---------------- scatter over compacted edge list ----------------
// 64 lanes per edge; lane handles 4 contiguous floats.
__global__ void scatter_c(const int* __restrict__ ei, const int* __restrict__ et,
                          const int* __restrict__ elist, const int* __restrict__ ectr, int ecap,
                          const int* __restrict__ mapSrc, const int* __restrict__ mapDst,
                          const float* __restrict__ hsrc,
                          float* __restrict__ Amsg, float* __restrict__ cnt,
                          int cntStride) {
    int g = blockIdx.x * blockDim.x + threadIdx.x;
    int ii = g >> 6, lane = g & 63;
    int n = imin(*ectr, ecap);
    if (ii >= n) return;
    int e = elist[ii];
    int d = ei[N_EDGES + e];
    int row = mapDst ? mapDst[d] : d;     // conv2: dst < BATCH is the row id
    if (row < 0) return;
    int s = mapSrc[ei[e]];
    if (s < 0) return;
    int r = et[e];
    float4 v = *(const float4*)(hsrc + (size_t)s * HID + lane * 4);
    float* dp = Amsg + (size_t)row * MSGW + (size_t)r * HID + lane * 4;
    atomicAdd(dp + 0, v.x);
    atomicAdd(dp + 1, v.y);
    atomicAdd(dp + 2, v.z);
    atomicAdd(dp + 3, v.w);
    if (lane == 0) atomicAdd(cnt + (size_t)r * cntStride + row, 1.0f);
}

// ---------------- linear1: h0c = relu(x[idx0] @ W1 + b1), bf16 MFMA ----------------
__global__ __launch_bounds__(256) void gemm1_mfma(
    const float* __restrict__ x, const int* __restrict__ idx0,
    const unsigned short* __restrict__ w1s, const float* __restrict__ b1,
    float* __restrict__ h0c, const int* __restrict__ Mptr, int Mcap)
{
    int M = imin(*Mptr, Mcap);
    int bm = blockIdx.x * 64;
    if (bm >= M) return;

    __shared__ unsigned short As[64][40];
    __shared__ unsigned short Bs[256][40];

    int tid = threadIdx.x;
    int w = tid >> 6, lane = tid & 63;
    int l16 = lane & 15, lhi = lane >> 4;

    int ar = tid >> 2, ac = tid & 3;
    int gr = idx0[imin(bm + ar, M - 1)];
    const float* aptr = x + (size_t)gr * IN_DIM + ac * 8;

    f32x4 acc[16];
    #pragma unroll
    for (int i = 0; i < 16; i++) acc[i] = (f32x4)0.0f;

    for (int k0 = 0; k0 < IN_DIM; k0 += 32) {
        float4 a0 = *(const float4*)(aptr + k0);
        float4 a1 = *(const float4*)(aptr + k0 + 4);
        unsigned int p0 = (unsigned int)f2bf(a0.x) | ((unsigned int)f2bf(a0.y) << 16);
        unsigned int p1 = (unsigned int)f2bf(a0.z) | ((unsigned int)f2bf(a0.w) << 16);
        unsigned int p2 = (unsigned int)f2bf(a1.x) | ((unsigned int)f2bf(a1.y) << 16);
        unsigned int p3 = (unsigned int)f2bf(a1.z) | ((unsigned int)f2bf(a1.w) << 16);
        *(uint4*)&As[ar][ac * 8] = make_uint4(p0, p1, p2, p3);

        const uint4* bsrc = (const uint4*)(w1s + ((size_t)(k0 >> 5) * 256 + tid) * 32);
        int bswz = (tid >> 3) & 3;
        uint4 b0 = bsrc[0], b1v = bsrc[1], b2 = bsrc[2], b3 = bsrc[3];
        *(uint4*)&Bs[tid][(0 ^ bswz) * 8] = b0;
        *(uint4*)&Bs[tid][(1 ^ bswz) * 8] = b1v;
        *(uint4*)&Bs[tid][(2 ^ bswz) * 8] = b2;
        *(uint4*)&Bs[tid][(3 ^ bswz) * 8] = b3;
        __syncthreads();

        bf16x8 af = *(bf16x8*)&As[w * 16 + l16][lhi * 8];
        #pragma unroll
        for (int f = 0; f < 16; f++) {
            int col = f * 16 + l16;
            bf16x8 bf = *(bf16x8*)&Bs[col][(lhi ^ ((col >> 3) & 3)) * 8];
            acc[f] = __builtin_amdgcn_mfma_f32_16x16x32_bf16(af, bf, acc[f], 0, 0, 0);
        }
        __syncthreads();
    }

    #pragma unroll
    for (int f = 0; f < 16; f++) {
        int col = f * 16 + l16;
        float bb = b1[col];
        #pragma unroll
        for (int reg = 0; reg < 4; reg++) {
            int row = bm + w * 16 + lhi * 4 + reg;
            if (row < M) h0c[(size_t)row * HID + col] = fmaxf(acc[f][reg] + bb, 0.0f);
        }
    }
}

// ---------------- conv GEMM: C = [root | msg*scale] @ Bcat + bias, bf16 MFMA ----------------
// A(row, k) = k<256 ? hsrc[map[idx?idx[row]:row]][k] : Amsg[row][k-256] * (1/max(cnt,1))
__global__ __launch_bounds__(256) void conv_mfma(
    const float* __restrict__ hsrc,
    const int* __restrict__ idx, const int* __restrict__ map,
    const float* __restrict__ Amsg,
    const float* __restrict__ cnt, int cntStride,
    const unsigned short* __restrict__ Bt, const float* __restrict__ bias,
    float* __restrict__ Cout, const int* __restrict__ Mptr, int Mcap)
{
    int M = Mptr ? imin(*Mptr, Mcap) : Mcap;
    int bm = blockIdx.x * 64;
    if (bm >= M) return;

    __shared__ unsigned short As[64][40];
    __shared__ unsigned short Bs[256][40];

    int tid = threadIdx.x;
    int w = tid >> 6, lane = tid & 63;
    int l16 = lane & 15, lhi = lane >> 4;

    int ar = tid >> 2, ac = tid & 3;
    int row = imin(bm + ar, M - 1);
    int node = idx ? idx[row] : row;
    int grow = map[node]; if (grow < 0) grow = 0;
    const float* rootp = hsrc + (size_t)grow * HID + ac * 8;
    const float* msgp  = Amsg + (size_t)row * MSGW + ac * 8;
    float sc[NREL];
    #pragma unroll
    for (int r = 0; r < NREL; r++)
        sc[r] = 1.0f / fmaxf(cnt[(size_t)r * cntStride + row], 1.0f);

    f32x4 acc[16];
    #pragma unroll
    for (int i = 0; i < 16; i++) acc[i] = (f32x4)0.0f;

    for (int k0 = 0; k0 < KCAT; k0 += 32) {
        float4 a0, a1;
        if (k0 < HID) {
            a0 = *(const float4*)(rootp + k0);
            a1 = *(const float4*)(rootp + k0 + 4);
        } else {
            float s = sc[(k0 - HID) >> 8];
            a0 = *(const float4*)(msgp + (k0 - HID));
            a1 = *(const float4*)(msgp + (k0 - HID) + 4);
            a0.x *= s; a0.y *= s; a0.z *= s; a0.w *= s;
            a1.x *= s; a1.y *= s; a1.z *= s; a1.w *= s;
        }
        unsigned int p0 = (unsigned int)f2bf(a0.x) | ((unsigned int)f2bf(a0.y) << 16);
        unsigned int p1 = (unsigned int)f2bf(a0.z) | ((unsigned int)f2bf(a0.w) << 16);
        unsigned int p2 = (unsigned int)f2bf(a1.x) | ((unsigned int)f2bf(a1.y) << 16);
        unsigned int p3 = (unsigned int)f2bf(a1.z) | ((unsigned int)f2bf(a1.w) << 16);
        *(uint4*)&As[ar][ac * 8] = make_uint4(p0, p1, p2, p3);

        const uint4* bsrc = (const uint4*)(Bt + ((size_t)(k0 >> 5) * 256 + tid) * 32);
        int bswz = (tid >> 3) & 3;
        uint4 b0 = bsrc[0], b1v = bsrc[1], b2 = bsrc[2], b3 = bsrc[3];
        *(uint4*)&Bs[tid][(0 ^ bswz) * 8] = b0;
        *(uint4*)&Bs[tid][(1 ^ bswz) * 8] = b1v;
        *(uint4*)&Bs[tid][(2 ^ bswz) * 8] = b2;
        *(uint4*)&Bs[tid][(3 ^ bswz) * 8] = b3;
        __syncthreads();

        bf16x8 af = *(bf16x8*)&As[w * 16 + l16][lhi * 8];
        #pragma unroll
        for (int f = 0; f < 16; f++) {
            int col = f * 16 + l16;
            bf16x8 bf = *(bf16x8*)&Bs[col][(lhi ^ ((col >> 3) & 3)) * 8];
            acc[f] = __builtin_amdgcn_mfma_f32_16x16x32_bf16(af, bf, acc[f], 0, 0, 0);
        }
        __syncthreads();
    }

    #pragma unroll
    for (int f = 0; f < 16; f++) {
        int col = f * 16 + l16;
        float bb = bias[col];
        #pragma unroll
        for (int reg = 0; reg < 4; reg++) {
            int r = bm + w * 16 + lhi * 4 + reg;
            if (r < M) Cout[(size_t)r * HID + col] = acc[f][reg] + bb;
        }
    }
}

// ---------------- lin2 + relu + classifier, fused (fp32) ----------------
// BM=32 rows/block, full 128 cols; K=256. Then logits = relu(.)@Wc + bc.
__global__ __launch_bounds__(256) void lin2_cls(
    const float* __restrict__ h2, const float* __restrict__ W2,
    const float* __restrict__ b2, const float* __restrict__ Wc,
    const float* __restrict__ bc, float* __restrict__ out)
{
    __shared__ float As[16][36];    // [k][row]
    __shared__ float Bs[16][132];   // [k][col]

    int tid = threadIdx.x;
    int bm = blockIdx.x * 32;
    int tx = tid & 15, ty = tid >> 4;      // cols tx*8..+7, rows ty*2..+1
    int brow = tid >> 4, bch = tid & 15;

    float acc[2][8] = {};

    for (int k0 = 0; k0 < HID; k0 += 16) {
        if (tid < 128) {
            int arow = tid >> 2, ach = tid & 3;
            float4 av = *(const float4*)(h2 + (size_t)(bm + arow) * HID + k0 + ach * 4);
            As[ach * 4 + 0][arow] = av.x;
            As[ach * 4 + 1][arow] = av.y;
            As[ach * 4 + 2][arow] = av.z;
            As[ach * 4 + 3][arow] = av.w;
        }
        const float* bp = W2 + (size_t)(k0 + brow) * OUT_DIM;
        *(float4*)&Bs[brow][bch * 4]      = *(const float4*)(bp + bch * 4);
        *(float4*)&Bs[brow][64 + bch * 4] = *(const float4*)(bp + 64 + bch * 4);
        __syncthreads();
        #pragma unroll
        for (int k = 0; k < 16; k++) {
            float a0 = As[k][ty * 2], a1 = As[k][ty * 2 + 1];
            float4 b0 = *(const float4*)&Bs[k][tx * 8];
            float4 b1 = *(const float4*)&Bs[k][tx * 8 + 4];
            acc[0][0] += a0 * b0.x; acc[0][1] += a0 * b0.y; acc[0][2] += a0 * b0.z; acc[0][3] += a0 * b0.w;
            acc[0][4] += a0 * b1.x; acc[0][5] += a0 * b1.y; acc[0][6] += a0 * b1.z; acc[0][7] += a0 * b1.w;
            acc[1][0] += a1 * b0.x; acc[1][1] += a1 * b0.y; acc[1][2] += a1 * b0.z; acc[1][3] += a1 * b0.w;
            acc[1][4] += a1 * b1.x; acc[1][5] += a1 * b1.y; acc[1][6] += a1 * b1.z; acc[1][7] += a1 * b1.w;
        }
        __syncthreads();
    }

    float s0[2] = {0.f, 0.f}, s1[2] = {0.f, 0.f};
    #pragma unroll
    for (int j = 0; j < 8; j++) {
        int col = tx * 8 + j;
        float w0 = Wc[col * 2 + 0], w1 = Wc[col * 2 + 1];
        float bb = b2[col];
        #pragma unroll
        for (int i = 0; i < 2; i++) {
            float h = fmaxf(acc[i][j] + bb, 0.0f);
            s0[i] += h * w0;
            s1[i] += h * w1;
        }
    }
    #pragma unroll
    for (int o = 1; o <= 8; o <<= 1) {
        #pragma unroll
        for (int i = 0; i < 2; i++) {
            s0[i] += __shfl_xor(s0[i], o);
            s1[i] += __shfl_xor(s1[i], o);
        }
    }
    if (tx == 0) {
        #pragma unroll
        for (int i = 0; i < 2; i++) {
            int row = bm + ty * 2 + i;
            out[row * 2 + 0] = s0[i] + bc[0];
            out[row * 2 + 1] = s1[i] + bc[1];
        }
    }
}

// ---------------- host ----------------

extern "C" void kernel_launch(void* const* d_in, const int* in_sizes, int n_in,
                              void* d_out, int out_size, void* d_ws, size_t ws_size,
                              hipStream_t stream) {
    const float* x      = (const float*)d_in[0];
    const int*   ei     = (const int*)d_in[1];
    const int*   et     = (const int*)d_in[2];
    const float* W1     = (const float*)d_in[4];
    const float* b1     = (const float*)d_in[5];
    const float* c1W    = (const float*)d_in[6];
    const float* c1root = (const float*)d_in[7];
    const float* c1bias = (const float*)d_in[8];
    const float* c2W    = (const float*)d_in[9];
    const float* c2root = (const float*)d_in[10];
    const float* c2bias = (const float*)d_in[11];
    const float* W2     = (const float*)d_in[12];
    const float* b2     = (const float*)d_in[13];
    const float* Wc     = (const float*)d_in[14];
    const float* bc     = (const float*)d_in[15];
    float* out = (float*)d_out;

    char* ws = (char*)d_ws;
    size_t off = 0;
    auto alloc = [&](size_t bytes) -> char* {
        char* p = ws + off;
        off = (off + bytes + 255) & ~(size_t)255;
        return p;
    };

    // --- zero block (single memset): ctrs | cnt1 | cnt2 | need1 | need0 | Amsg1 | Amsg2 ---
    size_t zb_ctr   = 16;
    size_t zb_cnt1  = (size_t)NREL * CAP1 * 4;
    size_t zb_cnt2  = (size_t)NREL * BATCH * 4;
    size_t zb_need  = (size_t)N_NODES * 4;
    size_t zb_amsg1 = (size_t)CAP1 * MSGW * 4;
    size_t zb_amsg2 = (size_t)BATCH * MSGW * 4;
    size_t zbytes = zb_ctr + zb_cnt1 + zb_cnt2 + 2 * zb_need + zb_amsg1 + zb_amsg2;
    char* zblock = alloc(zbytes);
    int*   n1ctr = (int*)zblock;
    int*   n0ctr = n1ctr + 1;
    int*   ectr1 = n1ctr + 2;
    int*   ectr2 = n1ctr + 3;
    float* cnt1  = (float*)(zblock + zb_ctr);
    float* cnt2  = (float*)(zblock + zb_ctr + zb_cnt1);
    int*   need1 = (int*)(zblock + zb_ctr + zb_cnt1 + zb_cnt2);
    int*   need0 = (int*)((char*)need1 + zb_need);
    float* Amsg1 = (float*)((char*)need0 + zb_need);
    float* Amsg2 = (float*)((char*)Amsg1 + zb_amsg1);

    int* map1  = (int*)alloc(N_NODES * 4);
    int* map0  = (int*)alloc(N_NODES * 4);
    int* idx1  = (int*)alloc(CAP1 * 4);
    int* idx0  = (int*)alloc(CAP0 * 4);
    int* elist1 = (int*)alloc(ECAP1 * 4);
    int* elist2 = (int*)alloc(ECAP2 * 4);
    float* h0c = (float*)alloc((size_t)CAP0 * HID * 4);
    float* h1c = (float*)alloc((size_t)CAP1 * HID * 4);
    float* h2  = (float*)alloc((size_t)BATCH * HID * 4);
    unsigned short* w1s = (unsigned short*)alloc((size_t)IN_DIM * HID * 2);
    unsigned short* B1s = (unsigned short*)alloc((size_t)KCAT * HID * 2);
    unsigned short* B2s = (unsigned short*)alloc((size_t)KCAT * HID * 2);
    (void)ws_size; (void)in_sizes; (void)n_in; (void)out_size;

    const int NB = 256;
    dim3 nodeGrid((N_NODES + NB - 1) / NB);
    dim3 edgeGrid((N_EDGES + NB - 1) / NB);
    const int PREP_T = IN_DIM * HID + 2 * KCAT * HID;

    // 1: zero
    hipMemsetAsync(zblock, 0, zbytes, stream);
    // 2: weight prep (bf16 tiled, builds concat-B)
    prep_weights<<<dim3((PREP_T + NB - 1) / NB), NB, 0, stream>>>(
        W1, c1root, c1W, c2root, c2W, w1s, B1s, B2s);
    // 3-5: dependency cone + edge lists + both compactions
    mark1c<<<edgeGrid, NB, 0, stream>>>(ei, need1, elist2, ectr2);
    mark0c<<<edgeGrid, NB, 0, stream>>>(ei, need1, need0, elist1, ectr1);
    compact_both<<<nodeGrid, NB, 0, stream>>>(need1, need0, idx1, map1, n1ctr, idx0, map0, n0ctr);
    // 6: h0c = relu(x[S0] @ W1 + b1)
    gemm1_mfma<<<dim3(CAP0 / 64), NB, 0, stream>>>(x, idx0, w1s, b1, h0c, n0ctr, CAP0);
    // 7-8: conv1
    scatter_c<<<dim3(ECAP1 * 64 / NB), NB, 0, stream>>>(ei, et, elist1, ectr1, ECAP1,
                                                        map0, map1, h0c, Amsg1, cnt1, CAP1);
    conv_mfma<<<dim3(CAP1 / 64), NB, 0, stream>>>(h0c, idx1, map0, Amsg1, cnt1, CAP1,
                                                  B1s, c1bias, h1c, n1ctr, CAP1);
    // 9-10: conv2 (rows = node ids 0..1023)
    scatter_c<<<dim3(ECAP2 * 64 / NB), NB, 0, stream>>>(ei, et, elist2, ectr2, ECAP2,
                                                        map1, nullptr, h1c, Amsg2, cnt2, BATCH);
    conv_mfma<<<dim3(BATCH / 64), NB, 0, stream>>>(h1c, nullptr, map1, Amsg2, cnt2, BATCH,
                                                   B2s, c2bias, h2, nullptr, BATCH);
    // 11: logits = relu(h2 @ W2 + b2) @ Wc + bc
    lin2_cls<<<dim3(BATCH / 32), NB, 0, stream>>>(h2, W2, b2, Wc, bc, out);
}

// Round 4
// 408.566 us; speedup vs baseline: 1.1893x; 1.0074x over previous
//
#include <hip/hip_runtime.h>

// RGCN pruned to the 2-hop cone of the first 1024 nodes.
// R4: hipMemsetAsync (measured 180us at 158 GB/s!) replaced by a custom
// zero kernel fused with weight prep. 10 graph nodes total.

#define N_NODES 100000
#define N_EDGES 400000
#define IN_DIM  768
#define HID     256
#define OUT_DIM 128
#define NREL    3
#define BATCH   1024
#define KCAT    1024   // HID*(NREL+1)
#define MSGW    768    // NREL*HID
#define CAP0    32768  // |S0| ~23K
#define CAP1    8192   // |S1| ~5K
#define ECAP1   32768  // edges into S1 ~20K
#define ECAP2   8192   // edges into S2 ~4.1K

typedef __attribute__((ext_vector_type(8))) short bf16x8;
typedef __attribute__((ext_vector_type(4))) float f32x4;

static __device__ __forceinline__ int imin(int a, int b) { return a < b ? a : b; }

static __device__ __forceinline__ unsigned short f2bf(float f) {
    union { float f; unsigned int u; } v; v.f = f;
    unsigned int r = v.u + 0x7FFFu + ((v.u >> 16) & 1u);   // RNE
    return (unsigned short)(r >> 16);
}

// ---------------- zero (custom fill) + weight prep, one kernel ----------------
// Threads [0, nz): zero 16B each of the accumulation block.
// Threads [nz, nz+P1+2*P2): produce 8 bf16 weights each (k-tiled layout).
__global__ __launch_bounds__(256) void zero_prep(
    uint4* __restrict__ zp, int nz,
    const float* __restrict__ W1,
    const float* __restrict__ c1root, const float* __restrict__ c1W,
    const float* __restrict__ c2root, const float* __restrict__ c2W,
    unsigned short* __restrict__ w1s,
    unsigned short* __restrict__ B1s,
    unsigned short* __restrict__ B2s)
{
    int t = blockIdx.x * blockDim.x + threadIdx.x;
    if (t < nz) { zp[t] = make_uint4(0u, 0u, 0u, 0u); return; }
    int u = t - nz;
    const int P1 = (IN_DIM * HID) / 8;   // 24576
    const int P2 = (KCAT * HID) / 8;     // 32768
    unsigned int pk[4];
    if (u < P1) {
        int base = u * 8;
        int j0 = base & 31, c = (base >> 5) & 255, s = base >> 13;
        #pragma unroll
        for (int q = 0; q < 4; q++) {
            unsigned short lo = f2bf(W1[((s * 32 + j0 + 2 * q) << 8) + c]);
            unsigned short hi = f2bf(W1[((s * 32 + j0 + 2 * q + 1) << 8) + c]);
            pk[q] = (unsigned int)lo | ((unsigned int)hi << 16);
        }
        *(uint4*)&w1s[base] = make_uint4(pk[0], pk[1], pk[2], pk[3]);
    } else if (u < P1 + 2 * P2) {
        int which2 = (u - P1) >= P2;
        const float* root = which2 ? c2root : c1root;
        const float* Wr   = which2 ? c2W : c1W;
        unsigned short* dst = which2 ? B2s : B1s;
        int base = ((u - P1) - (which2 ? P2 : 0)) * 8;
        int j0 = base & 31, c = (base >> 5) & 255, s = base >> 13;
        int k0 = s * 32 + j0;
        #pragma unroll
        for (int q = 0; q < 4; q++) {
            int ka = k0 + 2 * q, kb = ka + 1;
            float va = (ka < HID) ? root[(ka << 8) + c] : Wr[((ka - HID) << 8) + c];
            float vb = (kb < HID) ? root[(kb << 8) + c] : Wr[((kb - HID) << 8) + c];
            pk[q] = (unsigned int)f2bf(va) | ((unsigned int)f2bf(vb) << 16);
        }
        *(uint4*)&dst[base] = make_uint4(pk[0], pk[1], pk[2], pk[3]);
    }
}

// ---------------- set construction ----------------

__global__ void mark1c(const int* __restrict__ ei, int* __restrict__ need1,
                       int* __restrict__ elist2, int* __restrict__ ectr2) {
    int e = blockIdx.x * blockDim.x + threadIdx.x;
    if (e >= N_EDGES) return;
    if (ei[N_EDGES + e] < BATCH) {
        need1[ei[e]] = 1;   // benign same-value race
        int p = atomicAdd(ectr2, 1);
        if (p < ECAP2) elist2[p] = e;
    }
}

__global__ void mark0c(const int* __restrict__ ei, const int* __restrict__ need1,
                       int* __restrict__ need0,
                       int* __restrict__ elist1, int* __restrict__ ectr1) {
    int e = blockIdx.x * blockDim.x + threadIdx.x;
    if (e >= N_EDGES) return;
    int d = ei[N_EDGES + e];
    if (d < BATCH || need1[d]) {
        need0[ei[e]] = 1;
        int p = atomicAdd(ectr1, 1);
        if (p < ECAP1) elist1[p] = e;
    }
}

__global__ void compact_both(const int* __restrict__ need1, const int* __restrict__ need0,
                             int* __restrict__ idx1, int* __restrict__ map1, int* __restrict__ n1ctr,
                             int* __restrict__ idx0, int* __restrict__ map0, int* __restrict__ n0ctr) {
    int i = blockIdx.x * blockDim.x + threadIdx.x;
    if (i >= N_NODES) return;
    int f1 = (i < BATCH) | need1[i];
    int f0 = f1 | need0[i];
    if (f1) {
        int p = atomicAdd(n1ctr, 1);
        if (p < CAP1) { idx1[p] = i; map1[i] = p; } else map1[i] = -1;
    } else map1[i] = -1;
    if (f0) {
        int p = atomicAdd(n0ctr, 1);
        if (p < CAP0) { idx0[p] = i; map0[i] = p; } else map0[i] = -1;
    } else map0[i] = -1;
}

// ---------------- scatter over compacted edge list ----------------
__global__ void scatter_c(const int* __restrict__ ei, const int* __restrict__ et,
                          const int* __restrict__ elist, const int* __restrict__ ectr, int ecap,
                          const int* __restrict__ mapSrc, const int* __restrict__ mapDst,
                          const float* __restrict__ hsrc,
                          float* __restrict__ Amsg, float* __restrict__ cnt,
                          int cntStride) {
    int g = blockIdx.x * blockDim.x + threadIdx.x;
    int ii = g >> 6, lane = g & 63;
    int n = imin(*ectr, ecap);
    if (ii >= n) return;
    int e = elist[ii];
    int d = ei[N_EDGES + e];
    int row = mapDst ? mapDst[d] : d;
    if (row < 0) return;
    int s = mapSrc[ei[e]];
    if (s < 0) return;
    int r = et[e];
    float4 v = *(const float4*)(hsrc + (size_t)s * HID + lane * 4);
    float* dp = Amsg + (size_t)row * MSGW + (size_t)r * HID + lane * 4;
    atomicAdd(dp + 0, v.x);
    atomicAdd(dp + 1, v.y);
    atomicAdd(dp + 2, v.z);
    atomicAdd(dp + 3, v.w);
    if (lane == 0) atomicAdd(cnt + (size_t)r * cntStride + row, 1.0f);
}

// ---------------- linear1: h0c = relu(x[idx0] @ W1 + b1), bf16 MFMA ----------------
__global__ __launch_bounds__(256) void gemm1_mfma(
    const float* __restrict__ x, const int* __restrict__ idx0,
    const unsigned short* __restrict__ w1s, const float* __restrict__ b1,
    float* __restrict__ h0c, const int* __restrict__ Mptr, int Mcap)
{
    int M = imin(*Mptr, Mcap);
    int bm = blockIdx.x * 64;
    if (bm >= M) return;

    __shared__ unsigned short As[64][40];
    __shared__ unsigned short Bs[256][40];

    int tid = threadIdx.x;
    int w = tid >> 6, lane = tid & 63;
    int l16 = lane & 15, lhi = lane >> 4;

    int ar = tid >> 2, ac = tid & 3;
    int gr = idx0[imin(bm + ar, M - 1)];
    const float* aptr = x + (size_t)gr * IN_DIM + ac * 8;

    f32x4 acc[16];
    #pragma unroll
    for (int i = 0; i < 16; i++) acc[i] = (f32x4)0.0f;

    for (int k0 = 0; k0 < IN_DIM; k0 += 32) {
        float4 a0 = *(const float4*)(aptr + k0);
        float4 a1 = *(const float4*)(aptr + k0 + 4);
        unsigned int p0 = (unsigned int)f2bf(a0.x) | ((unsigned int)f2bf(a0.y) << 16);
        unsigned int p1 = (unsigned int)f2bf(a0.z) | ((unsigned int)f2bf(a0.w) << 16);
        unsigned int p2 = (unsigned int)f2bf(a1.x) | ((unsigned int)f2bf(a1.y) << 16);
        unsigned int p3 = (unsigned int)f2bf(a1.z) | ((unsigned int)f2bf(a1.w) << 16);
        *(uint4*)&As[ar][ac * 8] = make_uint4(p0, p1, p2, p3);

        const uint4* bsrc = (const uint4*)(w1s + ((size_t)(k0 >> 5) * 256 + tid) * 32);
        int bswz = (tid >> 3) & 3;
        uint4 b0 = bsrc[0], b1v = bsrc[1], b2 = bsrc[2], b3 = bsrc[3];
        *(uint4*)&Bs[tid][(0 ^ bswz) * 8] = b0;
        *(uint4*)&Bs[tid][(1 ^ bswz) * 8] = b1v;
        *(uint4*)&Bs[tid][(2 ^ bswz) * 8] = b2;
        *(uint4*)&Bs[tid][(3 ^ bswz) * 8] = b3;
        __syncthreads();

        bf16x8 af = *(bf16x8*)&As[w * 16 + l16][lhi * 8];
        #pragma unroll
        for (int f = 0; f < 16; f++) {
            int col = f * 16 + l16;
            bf16x8 bf = *(bf16x8*)&Bs[col][(lhi ^ ((col >> 3) & 3)) * 8];
            acc[f] = __builtin_amdgcn_mfma_f32_16x16x32_bf16(af, bf, acc[f], 0, 0, 0);
        }
        __syncthreads();
    }

    #pragma unroll
    for (int f = 0; f < 16; f++) {
        int col = f * 16 + l16;
        float bb = b1[col];
        #pragma unroll
        for (int reg = 0; reg < 4; reg++) {
            int row = bm + w * 16 + lhi * 4 + reg;
            if (row < M) h0c[(size_t)row * HID + col] = fmaxf(acc[f][reg] + bb, 0.0f);
        }
    }
}

// ---------------- conv GEMM: C = [root | msg*scale] @ Bcat + bias, bf16 MFMA ----------------
__global__ __launch_bounds__(256) void conv_mfma(
    const float* __restrict__ hsrc,
    const int* __restrict__ idx, const int* __restrict__ map,
    const float* __restrict__ Amsg,
    const float* __restrict__ cnt, int cntStride,
    const unsigned short* __restrict__ Bt, const float* __restrict__ bias,
    float* __restrict__ Cout, const int* __restrict__ Mptr, int Mcap)
{
    int M = Mptr ? imin(*Mptr, Mcap) : Mcap;
    int bm = blockIdx.x * 64;
    if (bm >= M) return;

    __shared__ unsigned short As[64][40];
    __shared__ unsigned short Bs[256][40];

    int tid = threadIdx.x;
    int w = tid >> 6, lane = tid & 63;
    int l16 = lane & 15, lhi = lane >> 4;

    int ar = tid >> 2, ac = tid & 3;
    int row = imin(bm + ar, M - 1);
    int node = idx ? idx[row] : row;
    int grow = map[node]; if (grow < 0) grow = 0;
    const float* rootp = hsrc + (size_t)grow * HID + ac * 8;
    const float* msgp  = Amsg + (size_t)row * MSGW + ac * 8;
    float sc[NREL];
    #pragma unroll
    for (int r = 0; r < NREL; r++)
        sc[r] = 1.0f / fmaxf(cnt[(size_t)r * cntStride + row], 1.0f);

    f32x4 acc[16];
    #pragma unroll
    for (int i = 0; i < 16; i++) acc[i] = (f32x4)0.0f;

    for (int k0 = 0; k0 < KCAT; k0 += 32) {
        float4 a0, a1;
        if (k0 < HID) {
            a0 = *(const float4*)(rootp + k0);
            a1 = *(const float4*)(rootp + k0 + 4);
        } else {
            float s = sc[(k0 - HID) >> 8];
            a0 = *(const float4*)(msgp + (k0 - HID));
            a1 = *(const float4*)(msgp + (k0 - HID) + 4);
            a0.x *= s; a0.y *= s; a0.z *= s; a0.w *= s;
            a1.x *= s; a1.y *= s; a1.z *= s; a1.w *= s;
        }
        unsigned int p0 = (unsigned int)f2bf(a0.x) | ((unsigned int)f2bf(a0.y) << 16);
        unsigned int p1 = (unsigned int)f2bf(a0.z) | ((unsigned int)f2bf(a0.w) << 16);
        unsigned int p2 = (unsigned int)f2bf(a1.x) | ((unsigned int)f2bf(a1.y) << 16);
        unsigned int p3 = (unsigned int)f2bf(a1.z) | ((unsigned int)f2bf(a1.w) << 16);
        *(uint4*)&As[ar][ac * 8] = make_uint4(p0, p1, p2, p3);

        const uint4* bsrc = (const uint4*)(Bt + ((size_t)(k0 >> 5) * 256 + tid) * 32);
        int bswz = (tid >> 3) & 3;
        uint4 b0 = bsrc[0], b1v = bsrc[1], b2 = bsrc[2], b3 = bsrc[3];
        *(uint4*)&Bs[tid][(0 ^ bswz) * 8] = b0;
        *(uint4*)&Bs[tid][(1 ^ bswz) * 8] = b1v;
        *(uint4*)&Bs[tid][(2 ^ bswz) * 8] = b2;
        *(uint4*)&Bs[tid][(3 ^ bswz) * 8] = b3;
        __syncthreads();

        bf16x8 af = *(bf16x8*)&As[w * 16 + l16][lhi * 8];
        #pragma unroll
        for (int f = 0; f < 16; f++) {
            int col = f * 16 + l16;
            bf16x8 bf = *(bf16x8*)&Bs[col][(lhi ^ ((col >> 3) & 3)) * 8];
            acc[f] = __builtin_amdgcn_mfma_f32_16x16x32_bf16(af, bf, acc[f], 0, 0, 0);
        }
        __syncthreads();
    }

    #pragma unroll
    for (int f = 0; f < 16; f++) {
        int col = f * 16 + l16;
        float bb = bias[col];
        #pragma unroll
        for (int reg = 0; reg < 4; reg++) {
            int r = bm + w * 16 + lhi * 4 + reg;
            if (r < M) Cout[(size_t)r * HID + col] = acc[f][reg] + bb;
        }
    }
}

// ---------------- lin2 + relu + classifier, fused (fp32) ----------------
__global__ __launch_bounds__(256) void lin2_cls(
    const float* __restrict__ h2, const float* __restrict__ W2,
    const float* __restrict__ b2, const float* __restrict__ Wc,
    const float* __restrict__ bc, float* __restrict__ out)
{
    __shared__ float As[16][36];
    __shared__ float Bs[16][132];

    int tid = threadIdx.x;
    int bm = blockIdx.x * 32;
    int tx = tid & 15, ty = tid >> 4;
    int brow = tid >> 4, bch = tid & 15;

    float acc[2][8] = {};

    for (int k0 = 0; k0 < HID; k0 += 16) {
        if (tid < 128) {
            int arow = tid >> 2, ach = tid & 3;
            float4 av = *(const float4*)(h2 + (size_t)(bm + arow) * HID + k0 + ach * 4);
            As[ach * 4 + 0][arow] = av.x;
            As[ach * 4 + 1][arow] = av.y;
            As[ach * 4 + 2][arow] = av.z;
            As[ach * 4 + 3][arow] = av.w;
        }
        const float* bp = W2 + (size_t)(k0 + brow) * OUT_DIM;
        *(float4*)&Bs[brow][bch * 4]      = *(const float4*)(bp + bch * 4);
        *(float4*)&Bs[brow][64 + bch * 4] = *(const float4*)(bp + 64 + bch * 4);
        __syncthreads();
        #pragma unroll
        for (int k = 0; k < 16; k++) {
            float a0 = As[k][ty * 2], a1 = As[k][ty * 2 + 1];
            float4 b0 = *(const float4*)&Bs[k][tx * 8];
            float4 b1 = *(const float4*)&Bs[k][tx * 8 + 4];
            acc[0][0] += a0 * b0.x; acc[0][1] += a0 * b0.y; acc[0][2] += a0 * b0.z; acc[0][3] += a0 * b0.w;
            acc[0][4] += a0 * b1.x; acc[0][5] += a0 * b1.y; acc[0][6] += a0 * b1.z; acc[0][7] += a0 * b1.w;
            acc[1][0] += a1 * b0.x; acc[1][1] += a1 * b0.y; acc[1][2] += a1 * b0.z; acc[1][3] += a1 * b0.w;
            acc[1][4] += a1 * b1.x; acc[1][5] += a1 * b1.y; acc[1][6] += a1 * b1.z; acc[1][7] += a1 * b1.w;
        }
        __syncthreads();
    }

    float s0[2] = {0.f, 0.f}, s1[2] = {0.f, 0.f};
    #pragma unroll
    for (int j = 0; j < 8; j++) {
        int col = tx * 8 + j;
        float w0 = Wc[col * 2 + 0], w1 = Wc[col * 2 + 1];
        float bb = b2[col];
        #pragma unroll
        for (int i = 0; i < 2; i++) {
            float h = fmaxf(acc[i][j] + bb, 0.0f);
            s0[i] += h * w0;
            s1[i] += h * w1;
        }
    }
    #pragma unroll
    for (int o = 1; o <= 8; o <<= 1) {
        #pragma unroll
        for (int i = 0; i < 2; i++) {
            s0[i] += __shfl_xor(s0[i], o);
            s1[i] += __shfl_xor(s1[i], o);
        }
    }
    if (tx == 0) {
        #pragma unroll
        for (int i = 0; i < 2; i++) {
            int row = bm + ty * 2 + i;
            out[row * 2 + 0] = s0[i] + bc[0];
            out[row * 2 + 1] = s1[i] + bc[1];
        }
    }
}

// ---------------- host ----------------

extern "C" void kernel_launch(void* const* d_in, const int* in_sizes, int n_in,
                              void* d_out, int out_size, void* d_ws, size_t ws_size,
                              hipStream_t stream) {
    const float* x      = (const float*)d_in[0];
    const int*   ei     = (const int*)d_in[1];
    const int*   et     = (const int*)d_in[2];
    const float* W1     = (const float*)d_in[4];
    const float* b1     = (const float*)d_in[5];
    const float* c1W    = (const float*)d_in[6];
    const float* c1root = (const float*)d_in[7];
    const float* c1bias = (const float*)d_in[8];
    const float* c2W    = (const float*)d_in[9];
    const float* c2root = (const float*)d_in[10];
    const float* c2bias = (const float*)d_in[11];
    const float* W2     = (const float*)d_in[12];
    const float* b2     = (const float*)d_in[13];
    const float* Wc     = (const float*)d_in[14];
    const float* bc     = (const float*)d_in[15];
    float* out = (float*)d_out;

    char* ws = (char*)d_ws;
    size_t off = 0;
    auto alloc = [&](size_t bytes) -> char* {
        char* p = ws + off;
        off = (off + bytes + 255) & ~(size_t)255;
        return p;
    };

    // --- zero block: ctrs | cnt1 | cnt2 | need1 | need0 | Amsg1 | Amsg2 ---
    size_t zb_ctr   = 16;
    size_t zb_cnt1  = (size_t)NREL * CAP1 * 4;
    size_t zb_cnt2  = (size_t)NREL * BATCH * 4;
    size_t zb_need  = (size_t)N_NODES * 4;
    size_t zb_amsg1 = (size_t)CAP1 * MSGW * 4;
    size_t zb_amsg2 = (size_t)BATCH * MSGW * 4;
    size_t zbytes = zb_ctr + zb_cnt1 + zb_cnt2 + 2 * zb_need + zb_amsg1 + zb_amsg2;
    char* zblock = alloc(zbytes);
    int*   n1ctr = (int*)zblock;
    int*   n0ctr = n1ctr + 1;
    int*   ectr1 = n1ctr + 2;
    int*   ectr2 = n1ctr + 3;
    float* cnt1  = (float*)(zblock + zb_ctr);
    float* cnt2  = (float*)(zblock + zb_ctr + zb_cnt1);
    int*   need1 = (int*)(zblock + zb_ctr + zb_cnt1 + zb_cnt2);
    int*   need0 = (int*)((char*)need1 + zb_need);
    float* Amsg1 = (float*)((char*)need0 + zb_need);
    float* Amsg2 = (float*)((char*)Amsg1 + zb_amsg1);

    int* map1  = (int*)alloc(N_NODES * 4);
    int* map0  = (int*)alloc(N_NODES * 4);
    int* idx1  = (int*)alloc(CAP1 * 4);
    int* idx0  = (int*)alloc(CAP0 * 4);
    int* elist1 = (int*)alloc(ECAP1 * 4);
    int* elist2 = (int*)alloc(ECAP2 * 4);
    float* h0c = (float*)alloc((size_t)CAP0 * HID * 4);
    float* h1c = (float*)alloc((size_t)CAP1 * HID * 4);
    float* h2  = (float*)alloc((size_t)BATCH * HID * 4);
    unsigned short* w1s = (unsigned short*)alloc((size_t)IN_DIM * HID * 2);
    unsigned short* B1s = (unsigned short*)alloc((size_t)KCAT * HID * 2);
    unsigned short* B2s = (unsigned short*)alloc((size_t)KCAT * HID * 2);
    (void)ws_size; (void)in_sizes; (void)n_in; (void)out_size;

    const int NB = 256;
    dim3 nodeGrid((N_NODES + NB - 1) / NB);
    dim3 edgeGrid((N_EDGES + NB - 1) / NB);

    // zero_prep: nz 16B-chunks of zero + (P1 + 2*P2) weight-prep threads
    int nz = (int)((zbytes + 15) / 16);
    int prep_threads = (IN_DIM * HID) / 8 + 2 * (KCAT * HID) / 8;
    int zp_total = nz + prep_threads;

    // 1: zero + weight prep (one node; replaces 180us rocclr fill)
    zero_prep<<<dim3((zp_total + NB - 1) / NB), NB, 0, stream>>>(
        (uint4*)zblock, nz, W1, c1root, c1W, c2root, c2W, w1s, B1s, B2s);
    // 2-4: dependency cone + edge lists + both compactions
    mark1c<<<edgeGrid, NB, 0, stream>>>(ei, need1, elist2, ectr2);
    mark0c<<<edgeGrid, NB, 0, stream>>>(ei, need1, need0, elist1, ectr1);
    compact_both<<<nodeGrid, NB, 0, stream>>>(need1, need0, idx1, map1, n1ctr, idx0, map0, n0ctr);
    // 5: h0c = relu(x[S0] @ W1 + b1)
    gemm1_mfma<<<dim3(CAP0 / 64), NB, 0, stream>>>(x, idx0, w1s, b1, h0c, n0ctr, CAP0);
    // 6-7: conv1
    scatter_c<<<dim3(ECAP1 * 64 / NB), NB, 0, stream>>>(ei, et, elist1, ectr1, ECAP1,
                                                        map0, map1, h0c, Amsg1, cnt1, CAP1);
    conv_mfma<<<dim3(CAP1 / 64), NB, 0, stream>>>(h0c, idx1, map0, Amsg1, cnt1, CAP1,
                                                  B1s, c1bias, h1c, n1ctr, CAP1);
    // 8-9: conv2 (rows = node ids 0..1023)
    scatter_c<<<dim3(ECAP2 * 64 / NB), NB, 0, stream>>>(ei, et, elist2, ectr2, ECAP2,
                                                        map1, nullptr, h1c, Amsg2, cnt2, BATCH);
    conv_mfma<<<dim3(BATCH / 64), NB, 0, stream>>>(h1c, nullptr, map1, Amsg2, cnt2, BATCH,
                                                   B2s, c2bias, h2, nullptr, BATCH);
    // 10: logits = relu(h2 @ W2 + b2) @ Wc + bc
    lin2_cls<<<dim3(BATCH / 32), NB, 0, stream>>>(h2, W2, b2, Wc, bc, out);
}